// Round 1
// baseline (531.277 us; speedup 1.0000x reference)
//
#include <hip/hip_runtime.h>
#include <hip/hip_bf16.h>

#define NB   4
#define NL   9
#define NQ   300
#define LQ   2700
#define NS   100
#define NC   256
#define NCLS 81
#define NPX  25600
#define EPSV 1e-6f

#define MASKS_BASE 32400
#define EMB_BASE   10272400   // 32400 + 4*100*160*160

__device__ inline float bf2f(unsigned int u) {
    union { unsigned int i; float f; } x; x.i = u << 16; return x.f;
}
__device__ inline unsigned short f2bf(float f) {
    __hip_bfloat16 h = __float2bfloat16(f);
    return *reinterpret_cast<unsigned short*>(&h);
}

// K1: w[b][s][q] = relu(dot(q_sig[b,q,:], seed[b,s,:])) * valid[b][s]
__global__ __launch_bounds__(256) void k_sim(const float* __restrict__ qsig,
                                             const float* __restrict__ seed,
                                             const int* __restrict__ mask,
                                             float* __restrict__ w) {
    __shared__ float lds_q[32][260];   // stride 260 to break 1KB-row bank conflict
    const int qc  = blockIdx.x;        // 0..84 (chunks of 32 queries)
    const int b   = blockIdx.y;
    const int tid = threadIdx.x;
    const int q0  = qc * 32;

    // stage 32 q_sig rows (coalesced float4)
    for (int it = tid; it < 32 * 64; it += 256) {
        const int r  = it >> 6;
        const int c4 = (it & 63) << 2;
        const int lq = q0 + r;
        if (lq < LQ) {
            const int l  = lq / NQ;
            const int qq = lq - l * NQ;
            const float4 v = *(const float4*)(qsig + ((size_t)((l * NB + b) * NQ + qq)) * NC + c4);
            *(float4*)&lds_q[r][c4] = v;   // 1040B row pitch: 16B aligned
        }
    }
    __syncthreads();

    const int qt = tid & 31;
    const int sg = tid >> 5;           // 0..7
    const int lq = q0 + qt;
    const bool qok = (lq < LQ);

    for (int i = 0; i < 4; ++i) {
        const int sb = i * 32 + sg * 4;
        if (sb >= NS) continue;        // covers s 0..99 (sb<=96 -> sb+3<=99)
        float acc[4] = {0.f, 0.f, 0.f, 0.f};
        const float* s0p = seed + ((size_t)(b * NS + sb)) * NC;
        for (int c4 = 0; c4 < 64; ++c4) {
            const float4 qv = *(const float4*)&lds_q[qt][c4 << 2];
            #pragma unroll
            for (int j = 0; j < 4; ++j) {
                const float4 sv = *(const float4*)(s0p + j * NC + (c4 << 2));
                acc[j] = fmaf(qv.x, sv.x, fmaf(qv.y, sv.y,
                         fmaf(qv.z, sv.z, fmaf(qv.w, sv.w, acc[j]))));
            }
        }
        if (qok) {
            #pragma unroll
            for (int j = 0; j < 4; ++j) {
                float wv = acc[j] > 0.f ? acc[j] : 0.f;
                if (mask[b * NS + sb + j] == 0) wv = 0.f;
                w[((size_t)(b * NS + sb + j)) * LQ + lq] = wv;
            }
        }
    }
}

// K2: rcp[b][s] = 1 / max(sum_q w[b][s][q], eps)
__global__ __launch_bounds__(256) void k_denom(const float* __restrict__ w,
                                               float* __restrict__ rcp) {
    const int s = blockIdx.x, b = blockIdx.y;
    const float* row = w + ((size_t)(b * NS + s)) * LQ;
    float sum = 0.f;
    for (int i = threadIdx.x; i < LQ / 4; i += 256) {   // 675 float4s
        const float4 v = *(const float4*)(row + i * 4);
        sum += v.x + v.y + v.z + v.w;
    }
    __shared__ float red[256];
    red[threadIdx.x] = sum;
    __syncthreads();
    for (int off = 128; off > 0; off >>= 1) {
        if (threadIdx.x < off) red[threadIdx.x] += red[threadIdx.x + off];
        __syncthreads();
    }
    if (threadIdx.x == 0) {
        float d = red[0];
        d = d > EPSV ? d : EPSV;
        rcp[b * NS + s] = 1.0f / d;
    }
}

// K3a: out_emb[b][s][c] += sum_{q in chunk} w[b][s][q] * q_emb[b,q,c]
__global__ __launch_bounds__(256) void k_emb(const float* __restrict__ w,
                                             const float* __restrict__ qemb,
                                             float* __restrict__ out_emb) {
    const int st = blockIdx.x;           // 13 s-tiles of 8
    const int b  = blockIdx.y;
    const int qs = blockIdx.z;           // 8 q-splits
    const int q0 = qs * 338;
    const int q1 = min(q0 + 338, LQ);
    const int cl = threadIdx.x & 63;
    const int sl = threadIdx.x >> 6;     // 0..3
    const int c  = cl << 2;
    const int s0 = st * 8 + sl * 2;
    if (s0 >= NS) return;                // s0 even <= 98, so s0+1 <= 99 ok
    const float* w0 = w + ((size_t)(b * NS + s0)) * LQ;
    const float* w1 = w0 + LQ;
    float a0x=0,a0y=0,a0z=0,a0w=0, a1x=0,a1y=0,a1z=0,a1w=0;
    for (int q = q0; q < q1; ++q) {
        const int l  = q / NQ;
        const int qq = q - l * NQ;
        const float4 ev = *(const float4*)(qemb + ((size_t)((l * NB + b) * NQ + qq)) * NC + c);
        const float w0v = w0[q];
        const float w1v = w1[q];
        a0x = fmaf(w0v, ev.x, a0x); a0y = fmaf(w0v, ev.y, a0y);
        a0z = fmaf(w0v, ev.z, a0z); a0w = fmaf(w0v, ev.w, a0w);
        a1x = fmaf(w1v, ev.x, a1x); a1y = fmaf(w1v, ev.y, a1y);
        a1z = fmaf(w1v, ev.z, a1z); a1w = fmaf(w1v, ev.w, a1w);
    }
    float* d0 = out_emb + ((size_t)(b * NS + s0)) * NC + c;
    atomicAdd(d0 + 0, a0x); atomicAdd(d0 + 1, a0y);
    atomicAdd(d0 + 2, a0z); atomicAdd(d0 + 3, a0w);
    float* d1 = d0 + NC;
    atomicAdd(d1 + 0, a1x); atomicAdd(d1 + 1, a1y);
    atomicAdd(d1 + 2, a1z); atomicAdd(d1 + 3, a1w);
}

// K3b: out_cls[b][s][c] += sum_{q in chunk} w[b][s][q] * q_cls[b,q,c]
__global__ __launch_bounds__(256) void k_cls(const float* __restrict__ w,
                                             const float* __restrict__ qcls,
                                             float* __restrict__ out_cls) {
    const int st = blockIdx.x;
    const int b  = blockIdx.y;
    const int qs = blockIdx.z;
    const int q0 = qs * 338;
    const int q1 = min(q0 + 338, LQ);
    const int cl = threadIdx.x & 31;
    const int sl = threadIdx.x >> 5;     // 0..7
    const int c  = cl << 2;
    const int s  = st * 8 + sl;
    if (s >= NS || c >= NCLS) return;
    const int nc = min(4, NCLS - c);
    const float* wr = w + ((size_t)(b * NS + s)) * LQ;
    float a[4] = {0.f, 0.f, 0.f, 0.f};
    for (int q = q0; q < q1; ++q) {
        const int l  = q / NQ;
        const int qq = q - l * NQ;
        const float* er = qcls + ((size_t)((l * NB + b) * NQ + qq)) * NCLS + c;
        const float wv = wr[q];
        #pragma unroll
        for (int k = 0; k < 4; ++k)
            if (k < nc) a[k] = fmaf(wv, er[k], a[k]);
    }
    float* dst = out_cls + ((size_t)(b * NS + s)) * NCLS + c;
    #pragma unroll
    for (int k = 0; k < 4; ++k)
        if (k < nc) atomicAdd(dst + k, a[k]);
}

// K4: scale accumulated sums by rcp (finalizes proto_cls and proto_mask_emb)
__global__ __launch_bounds__(256) void k_fin(float* __restrict__ out,
                                             const float* __restrict__ rcp) {
    const int i = blockIdx.x * 256 + threadIdx.x;
    if (i < NB * NS * NCLS) {
        const int b = i / (NS * NCLS);
        const int s = (i / NCLS) % NS;
        out[i] *= rcp[b * NS + s];
    } else if (i < NB * NS * NCLS + NB * NS * NC) {
        const int j = i - NB * NS * NCLS;
        const int b = j / (NS * NC);
        const int s = (j >> 8) % NS;
        out[EMB_BASE + j] *= rcp[b * NS + s];
    }
}

// K5: proto_masks[b][s][px] = sum_c proto_emb[b][s][c] * mf[b][c][px]
__global__ __launch_bounds__(256) void k_masks(const float* __restrict__ emb,
                                               const float* __restrict__ mf,
                                               float* __restrict__ outm) {
    __shared__ unsigned short AT[NC * 104];  // A transposed, bf16, padded s-dim
    const int b   = blockIdx.y;
    const int px0 = blockIdx.x * 64;
    const int tid = threadIdx.x;

    for (int i = tid; i < NS * NC; i += 256) {
        const int s = i >> 8;
        const int c = i & 255;
        const float v = emb[((size_t)(b * NS + s)) * NC + c];
        AT[c * 104 + s] = f2bf(v);
    }
    __syncthreads();

    const int pg = tid & 7;           // 8 px-groups of 8
    const int sg = tid >> 3;          // 0..31, active sg<25
    const int s0 = sg * 4;
    if (s0 >= NS) return;
    const int px = px0 + pg * 8;

    float acc[4][8];
    #pragma unroll
    for (int j = 0; j < 4; ++j)
        #pragma unroll
        for (int p = 0; p < 8; ++p) acc[j][p] = 0.f;

    const float* bptr = mf + ((size_t)b * NC) * NPX + px;
    #pragma unroll 2
    for (int c = 0; c < NC; ++c) {
        const float4 b0 = *(const float4*)(bptr);
        const float4 b1 = *(const float4*)(bptr + 4);
        bptr += NPX;
        const uint2 au = *(const uint2*)&AT[c * 104 + s0];   // 8B aligned
        float a[4];
        a[0] = bf2f(au.x & 0xffffu); a[1] = bf2f(au.x >> 16);
        a[2] = bf2f(au.y & 0xffffu); a[3] = bf2f(au.y >> 16);
        #pragma unroll
        for (int j = 0; j < 4; ++j) {
            acc[j][0] = fmaf(a[j], b0.x, acc[j][0]);
            acc[j][1] = fmaf(a[j], b0.y, acc[j][1]);
            acc[j][2] = fmaf(a[j], b0.z, acc[j][2]);
            acc[j][3] = fmaf(a[j], b0.w, acc[j][3]);
            acc[j][4] = fmaf(a[j], b1.x, acc[j][4]);
            acc[j][5] = fmaf(a[j], b1.y, acc[j][5]);
            acc[j][6] = fmaf(a[j], b1.z, acc[j][6]);
            acc[j][7] = fmaf(a[j], b1.w, acc[j][7]);
        }
    }

    float* op = outm + ((size_t)(b * NS + s0)) * NPX + px;
    #pragma unroll
    for (int j = 0; j < 4; ++j) {     // s0+3 <= 99 guaranteed (s0 <= 96)
        *(float4*)(op)     = make_float4(acc[j][0], acc[j][1], acc[j][2], acc[j][3]);
        *(float4*)(op + 4) = make_float4(acc[j][4], acc[j][5], acc[j][6], acc[j][7]);
        op += NPX;
    }
}

extern "C" void kernel_launch(void* const* d_in, const int* in_sizes, int n_in,
                              void* d_out, int out_size, void* d_ws, size_t ws_size,
                              hipStream_t stream) {
    const float* qcls = (const float*)d_in[0];
    const float* qemb = (const float*)d_in[1];
    const float* qsig = (const float*)d_in[2];
    const float* seed = (const float*)d_in[3];
    const float* mf   = (const float*)d_in[4];
    const int*   mask = (const int*)d_in[5];

    float* out       = (float*)d_out;
    float* out_cls   = out;
    float* out_masks = out + MASKS_BASE;
    float* out_emb   = out + EMB_BASE;

    float* w   = (float*)d_ws;                    // [4][100][2700]
    float* rcp = w + (size_t)NB * NS * LQ;        // [400]

    hipMemsetAsync(out_cls, 0, (size_t)NB * NS * NCLS * sizeof(float), stream);
    hipMemsetAsync(out_emb, 0, (size_t)NB * NS * NC * sizeof(float), stream);

    k_sim  <<<dim3(85, NB),    256, 0, stream>>>(qsig, seed, mask, w);
    k_denom<<<dim3(NS, NB),    256, 0, stream>>>(w, rcp);
    k_emb  <<<dim3(13, NB, 8), 256, 0, stream>>>(w, qemb, out_emb);
    k_cls  <<<dim3(13, NB, 8), 256, 0, stream>>>(w, qcls, out_cls);
    k_fin  <<<527,             256, 0, stream>>>(out, rcp);
    k_masks<<<dim3(400, NB),   256, 0, stream>>>(out_emb, mf, out_masks);
}

// Round 2
// 222.849 us; speedup vs baseline: 2.3840x; 2.3840x over previous
//
#include <hip/hip_runtime.h>
#include <hip/hip_bf16.h>

#define NB   4
#define NL   9
#define NQ   300
#define LQ   2700
#define NS   100
#define NC   256
#define NCLS 81
#define NPX  25600
#define EPSV 1e-6f

#define MASKS_BASE 32400
#define EMB_BASE   10272400   // 32400 + 4*100*160*160

__device__ inline float lo16(unsigned int u) {
    union { unsigned int i; float f; } x; x.i = u << 16; return x.f;
}
__device__ inline float hi16(unsigned int u) {
    union { unsigned int i; float f; } x; x.i = u & 0xffff0000u; return x.f;
}
__device__ inline unsigned short f2bf(float f) {
    __hip_bfloat16 h = __float2bfloat16(f);
    return *reinterpret_cast<unsigned short*>(&h);
}

// K1: w[b][s][q] = relu(dot(q_sig[b,q,:], seed[b,s,:])) * valid[b][s]
__global__ __launch_bounds__(256) void k_sim(const float* __restrict__ qsig,
                                             const float* __restrict__ seed,
                                             const int* __restrict__ mask,
                                             float* __restrict__ w) {
    __shared__ float lds_q[32][260];   // stride 260 to break 1KB-row bank conflict
    const int qc  = blockIdx.x;        // 0..84 (chunks of 32 queries)
    const int b   = blockIdx.y;
    const int tid = threadIdx.x;
    const int q0  = qc * 32;

    for (int it = tid; it < 32 * 64; it += 256) {
        const int r  = it >> 6;
        const int c4 = (it & 63) << 2;
        const int lq = q0 + r;
        if (lq < LQ) {
            const int l  = lq / NQ;
            const int qq = lq - l * NQ;
            const float4 v = *(const float4*)(qsig + ((size_t)((l * NB + b) * NQ + qq)) * NC + c4);
            *(float4*)&lds_q[r][c4] = v;
        }
    }
    __syncthreads();

    const int qt = tid & 31;
    const int sg = tid >> 5;           // 0..7
    const int lq = q0 + qt;
    const bool qok = (lq < LQ);

    for (int i = 0; i < 4; ++i) {
        const int sb = i * 32 + sg * 4;
        if (sb >= NS) continue;
        float acc[4] = {0.f, 0.f, 0.f, 0.f};
        const float* s0p = seed + ((size_t)(b * NS + sb)) * NC;
        for (int c4 = 0; c4 < 64; ++c4) {
            const float4 qv = *(const float4*)&lds_q[qt][c4 << 2];
            #pragma unroll
            for (int j = 0; j < 4; ++j) {
                const float4 sv = *(const float4*)(s0p + j * NC + (c4 << 2));
                acc[j] = fmaf(qv.x, sv.x, fmaf(qv.y, sv.y,
                         fmaf(qv.z, sv.z, fmaf(qv.w, sv.w, acc[j]))));
            }
        }
        if (qok) {
            #pragma unroll
            for (int j = 0; j < 4; ++j) {
                float wv = acc[j] > 0.f ? acc[j] : 0.f;
                if (mask[b * NS + sb + j] == 0) wv = 0.f;
                w[((size_t)(b * NS + sb + j)) * LQ + lq] = wv;
            }
        }
    }
}

// K2: rcp[b][s] = 1 / max(sum_q w[b][s][q], eps)
__global__ __launch_bounds__(256) void k_denom(const float* __restrict__ w,
                                               float* __restrict__ rcp) {
    const int s = blockIdx.x, b = blockIdx.y;
    const float* row = w + ((size_t)(b * NS + s)) * LQ;
    float sum = 0.f;
    for (int i = threadIdx.x; i < LQ / 4; i += 256) {
        const float4 v = *(const float4*)(row + i * 4);
        sum += v.x + v.y + v.z + v.w;
    }
    __shared__ float red[256];
    red[threadIdx.x] = sum;
    __syncthreads();
    for (int off = 128; off > 0; off >>= 1) {
        if (threadIdx.x < off) red[threadIdx.x] += red[threadIdx.x + off];
        __syncthreads();
    }
    if (threadIdx.x == 0) {
        float d = red[0];
        d = d > EPSV ? d : EPSV;
        rcp[b * NS + s] = 1.0f / d;
    }
}

// K3: out[b][s][c] += sum_{q in chunk} w[b][s][q] * src[b,q,c]
// Fused emb (tiles 0-3) + cls (tiles 4-5). w chunk staged in LDS,
// each thread: 25 s-accumulators, one c column. Split-K atomics.
__global__ __launch_bounds__(256) void k_embcls(const float* __restrict__ w,
                                                const float* __restrict__ qemb,
                                                const float* __restrict__ qcls,
                                                float* __restrict__ out_emb,
                                                float* __restrict__ out_cls) {
    __shared__ float W[NS * 128];      // [100 s][128 q] chunk, 51.2 KB
    const int t  = blockIdx.x;         // 0..5 (c-tile)
    const int b  = blockIdx.y;
    const int qc = blockIdx.z;         // 0..21
    const int q0 = qc * 128;
    const int q1 = min(128, LQ - q0);  // 128 or 12; always %4==0

    for (int i = threadIdx.x; i < NS * 32; i += 256) {
        const int s  = i >> 5;
        const int q4 = (i & 31) << 2;
        if (q4 < q1)
            *(float4*)&W[s * 128 + q4] =
                *(const float4*)(w + ((size_t)(b * NS + s)) * LQ + q0 + q4);
    }
    __syncthreads();

    const int cl = threadIdx.x & 63;
    const int y  = threadIdx.x >> 6;   // 0..3 -> s base y*25
    const float* src; int ncols, c0; float* dst;
    if (t < 4) { src = qemb; ncols = NC;   c0 = t * 64;       dst = out_emb; }
    else       { src = qcls; ncols = NCLS; c0 = (t - 4) * 64; dst = out_cls; }
    const int  c   = c0 + cl;
    const bool act = (c < ncols);

    float acc[25];
    #pragma unroll
    for (int j = 0; j < 25; ++j) acc[j] = 0.f;

    for (int qq = 0; qq < q1; qq += 4) {
        float bv[4];
        #pragma unroll
        for (int k = 0; k < 4; ++k) {
            const int q = q0 + qq + k;
            const int l = q / NQ;
            const int r = q - l * NQ;
            bv[k] = act ? src[((size_t)((l * NB + b) * NQ + r)) * ncols + c] : 0.f;
        }
        const float* wp = &W[(y * 25) * 128 + qq];
        #pragma unroll
        for (int j = 0; j < 25; ++j) {
            const float4 wv = *(const float4*)(wp + j * 128);  // wave-broadcast
            acc[j] = fmaf(wv.x, bv[0], fmaf(wv.y, bv[1],
                     fmaf(wv.z, bv[2], fmaf(wv.w, bv[3], acc[j]))));
        }
    }
    if (act) {
        #pragma unroll
        for (int j = 0; j < 25; ++j) {
            const int s = y * 25 + j;   // 0..99 exactly
            atomicAdd(dst + ((size_t)(b * NS + s)) * ncols + c, acc[j]);
        }
    }
}

// K4: scale accumulated sums by rcp (finalizes proto_cls and proto_mask_emb)
__global__ __launch_bounds__(256) void k_fin(float* __restrict__ out,
                                             const float* __restrict__ rcp) {
    const int i = blockIdx.x * 256 + threadIdx.x;
    if (i < NB * NS * NCLS) {
        const int b = i / (NS * NCLS);
        const int s = (i / NCLS) % NS;
        out[i] *= rcp[b * NS + s];
    } else if (i < NB * NS * NCLS + NB * NS * NC) {
        const int j = i - NB * NS * NCLS;
        const int b = j / (NS * NC);
        const int s = (j >> 8) % NS;
        out[EMB_BASE + j] *= rcp[b * NS + s];
    }
}

// K5: proto_masks[b][s][px] = sum_c proto_emb[b][s][c] * mf[b][c][px]
// Register-blocked: thread = 13 s x 8 px (104 acc), A bf16 broadcast from LDS.
__global__ __launch_bounds__(256) void k_masks(const float* __restrict__ emb,
                                               const float* __restrict__ mf,
                                               float* __restrict__ outm) {
    __shared__ unsigned short AT[NC * 128];  // [c][chunk*16 + j], 64 KB
    const int b   = blockIdx.y;
    const int px0 = blockIdx.x * 256;
    const int tid = threadIdx.x;

    // stage A (normalized emb), bf16, chunk-padded: slot=ch*16+j -> s=ch*13+j
    for (int i = tid; i < NC * 128; i += 256) {
        const int c    = i >> 7;
        const int slot = i & 127;
        const int ch   = slot >> 4;
        const int j    = slot & 15;
        const int s    = ch * 13 + j;
        float v = 0.f;
        if (j < 13 && s < NS) v = emb[((size_t)(b * NS + s)) * NC + c];
        AT[i] = f2bf(v);
    }
    __syncthreads();

    const int x = tid & 31;            // px quad within tile
    const int y = tid >> 5;            // 0..7 = s-chunk
    const int pxa = px0 + x * 4;
    const int pxb = px0 + 128 + x * 4;

    float acc[13][8];
    #pragma unroll
    for (int j = 0; j < 13; ++j)
        #pragma unroll
        for (int p = 0; p < 8; ++p) acc[j][p] = 0.f;

    const float* bpa = mf + ((size_t)b * NC) * NPX + pxa;
    const float* bpb = mf + ((size_t)b * NC) * NPX + pxb;

    #pragma unroll 2
    for (int c = 0; c < NC; ++c) {
        const float4 b0 = *(const float4*)(bpa);
        const float4 b1 = *(const float4*)(bpb);
        bpa += NPX; bpb += NPX;
        const uint4 u0 = *(const uint4*)&AT[c * 128 + y * 16];      // slots 0..7
        const uint4 u1 = *(const uint4*)&AT[c * 128 + y * 16 + 8];  // slots 8..15
        float a[13];
        a[0]  = lo16(u0.x); a[1]  = hi16(u0.x);
        a[2]  = lo16(u0.y); a[3]  = hi16(u0.y);
        a[4]  = lo16(u0.z); a[5]  = hi16(u0.z);
        a[6]  = lo16(u0.w); a[7]  = hi16(u0.w);
        a[8]  = lo16(u1.x); a[9]  = hi16(u1.x);
        a[10] = lo16(u1.y); a[11] = hi16(u1.y);
        a[12] = lo16(u1.z);
        #pragma unroll
        for (int j = 0; j < 13; ++j) {
            acc[j][0] = fmaf(a[j], b0.x, acc[j][0]);
            acc[j][1] = fmaf(a[j], b0.y, acc[j][1]);
            acc[j][2] = fmaf(a[j], b0.z, acc[j][2]);
            acc[j][3] = fmaf(a[j], b0.w, acc[j][3]);
            acc[j][4] = fmaf(a[j], b1.x, acc[j][4]);
            acc[j][5] = fmaf(a[j], b1.y, acc[j][5]);
            acc[j][6] = fmaf(a[j], b1.z, acc[j][6]);
            acc[j][7] = fmaf(a[j], b1.w, acc[j][7]);
        }
    }

    #pragma unroll
    for (int j = 0; j < 13; ++j) {
        const int s = y * 13 + j;
        if (s < NS) {
            float* op = outm + ((size_t)(b * NS + s)) * NPX;
            *(float4*)(op + pxa) = make_float4(acc[j][0], acc[j][1], acc[j][2], acc[j][3]);
            *(float4*)(op + pxb) = make_float4(acc[j][4], acc[j][5], acc[j][6], acc[j][7]);
        }
    }
}

extern "C" void kernel_launch(void* const* d_in, const int* in_sizes, int n_in,
                              void* d_out, int out_size, void* d_ws, size_t ws_size,
                              hipStream_t stream) {
    const float* qcls = (const float*)d_in[0];
    const float* qemb = (const float*)d_in[1];
    const float* qsig = (const float*)d_in[2];
    const float* seed = (const float*)d_in[3];
    const float* mf   = (const float*)d_in[4];
    const int*   mask = (const int*)d_in[5];

    float* out       = (float*)d_out;
    float* out_cls   = out;
    float* out_masks = out + MASKS_BASE;
    float* out_emb   = out + EMB_BASE;

    float* w   = (float*)d_ws;                    // [4][100][2700]
    float* rcp = w + (size_t)NB * NS * LQ;        // [400]

    hipMemsetAsync(out_cls, 0, (size_t)NB * NS * NCLS * sizeof(float), stream);
    hipMemsetAsync(out_emb, 0, (size_t)NB * NS * NC * sizeof(float), stream);

    k_sim   <<<dim3(85, NB),     256, 0, stream>>>(qsig, seed, mask, w);
    k_denom <<<dim3(NS, NB),     256, 0, stream>>>(w, rcp);
    k_embcls<<<dim3(6, NB, 22),  256, 0, stream>>>(w, qemb, qcls, out_emb, out_cls);
    k_fin   <<<527,              256, 0, stream>>>(out, rcp);
    k_masks <<<dim3(100, NB),    256, 0, stream>>>(out_emb, mf, out_masks);
}

// Round 5
// 149.229 us; speedup vs baseline: 3.5601x; 1.4933x over previous
//
#include <hip/hip_runtime.h>
#include <hip/hip_bf16.h>

#define NB   4
#define NL   9
#define NQ   300
#define LQ   2700
#define NS   100
#define NC   256
#define NCLS 81
#define NPX  25600
#define EPSV 1e-6f

#define MASKS_BASE 32400
#define EMB_BASE   10272400   // 32400 + 4*100*160*160

#define A_STRIDE 264          // bf16 elems; 528B rows: 16B-aligned, 4-bank rotation

typedef short bf16x8 __attribute__((ext_vector_type(8)));
typedef short bf16x4 __attribute__((ext_vector_type(4)));
typedef float f32x4  __attribute__((ext_vector_type(4)));

__device__ inline unsigned short f2bf(float f) {
    __hip_bfloat16 h = __float2bfloat16(f);
    return *reinterpret_cast<unsigned short*>(&h);
}

// K1: w[b][s][q] = relu(dot(q_sig[b,q,:], seed[b,s,:])) * valid[b][s]
__global__ __launch_bounds__(256) void k_sim(const float* __restrict__ qsig,
                                             const float* __restrict__ seed,
                                             const int* __restrict__ mask,
                                             float* __restrict__ w) {
    __shared__ float lds_q[32][260];
    const int qc  = blockIdx.x;
    const int b   = blockIdx.y;
    const int tid = threadIdx.x;
    const int q0  = qc * 32;

    for (int it = tid; it < 32 * 64; it += 256) {
        const int r  = it >> 6;
        const int c4 = (it & 63) << 2;
        const int lq = q0 + r;
        if (lq < LQ) {
            const int l  = lq / NQ;
            const int qq = lq - l * NQ;
            const float4 v = *(const float4*)(qsig + ((size_t)((l * NB + b) * NQ + qq)) * NC + c4);
            *(float4*)&lds_q[r][c4] = v;
        }
    }
    __syncthreads();

    const int qt = tid & 31;
    const int sg = tid >> 5;
    const int lq = q0 + qt;
    const bool qok = (lq < LQ);

    for (int i = 0; i < 4; ++i) {
        const int sb = i * 32 + sg * 4;
        if (sb >= NS) continue;
        float acc[4] = {0.f, 0.f, 0.f, 0.f};
        const float* s0p = seed + ((size_t)(b * NS + sb)) * NC;
        for (int c4 = 0; c4 < 64; ++c4) {
            const float4 qv = *(const float4*)&lds_q[qt][c4 << 2];
            #pragma unroll
            for (int j = 0; j < 4; ++j) {
                const float4 sv = *(const float4*)(s0p + j * NC + (c4 << 2));
                acc[j] = fmaf(qv.x, sv.x, fmaf(qv.y, sv.y,
                         fmaf(qv.z, sv.z, fmaf(qv.w, sv.w, acc[j]))));
            }
        }
        if (qok) {
            #pragma unroll
            for (int j = 0; j < 4; ++j) {
                float wv = acc[j] > 0.f ? acc[j] : 0.f;
                if (mask[b * NS + sb + j] == 0) wv = 0.f;
                w[((size_t)(b * NS + sb + j)) * LQ + lq] = wv;
            }
        }
    }
}

// K2: rcp[b][s] = 1 / max(sum_q w[b][s][q], eps)
__global__ __launch_bounds__(256) void k_denom(const float* __restrict__ w,
                                               float* __restrict__ rcp) {
    const int s = blockIdx.x, b = blockIdx.y;
    const float* row = w + ((size_t)(b * NS + s)) * LQ;
    float sum = 0.f;
    for (int i = threadIdx.x; i < LQ / 4; i += 256) {
        const float4 v = *(const float4*)(row + i * 4);
        sum += v.x + v.y + v.z + v.w;
    }
    __shared__ float red[256];
    red[threadIdx.x] = sum;
    __syncthreads();
    for (int off = 128; off > 0; off >>= 1) {
        if (threadIdx.x < off) red[threadIdx.x] += red[threadIdx.x + off];
        __syncthreads();
    }
    if (threadIdx.x == 0) {
        float d = red[0];
        d = d > EPSV ? d : EPSV;
        rcp[b * NS + s] = 1.0f / d;
    }
}

// K3: fused emb+cls reduction over q, split-K atomics
__global__ __launch_bounds__(256) void k_embcls(const float* __restrict__ w,
                                                const float* __restrict__ qemb,
                                                const float* __restrict__ qcls,
                                                float* __restrict__ out_emb,
                                                float* __restrict__ out_cls) {
    __shared__ float W[NS * 128];
    const int t  = blockIdx.x;
    const int b  = blockIdx.y;
    const int qc = blockIdx.z;
    const int q0 = qc * 128;
    const int q1 = min(128, LQ - q0);

    for (int i = threadIdx.x; i < NS * 32; i += 256) {
        const int s  = i >> 5;
        const int q4 = (i & 31) << 2;
        if (q4 < q1)
            *(float4*)&W[s * 128 + q4] =
                *(const float4*)(w + ((size_t)(b * NS + s)) * LQ + q0 + q4);
    }
    __syncthreads();

    const int cl = threadIdx.x & 63;
    const int y  = threadIdx.x >> 6;
    const float* src; int ncols, c0; float* dst;
    if (t < 4) { src = qemb; ncols = NC;   c0 = t * 64;       dst = out_emb; }
    else       { src = qcls; ncols = NCLS; c0 = (t - 4) * 64; dst = out_cls; }
    const int  c   = c0 + cl;
    const bool act = (c < ncols);

    float acc[25];
    #pragma unroll
    for (int j = 0; j < 25; ++j) acc[j] = 0.f;

    for (int qq = 0; qq < q1; qq += 4) {
        float bv[4];
        #pragma unroll
        for (int k = 0; k < 4; ++k) {
            const int q = q0 + qq + k;
            const int l = q / NQ;
            const int r = q - l * NQ;
            bv[k] = act ? src[((size_t)((l * NB + b) * NQ + r)) * ncols + c] : 0.f;
        }
        const float* wp = &W[(y * 25) * 128 + qq];
        #pragma unroll
        for (int j = 0; j < 25; ++j) {
            const float4 wv = *(const float4*)(wp + j * 128);
            acc[j] = fmaf(wv.x, bv[0], fmaf(wv.y, bv[1],
                     fmaf(wv.z, bv[2], fmaf(wv.w, bv[3], acc[j]))));
        }
    }
    if (act) {
        #pragma unroll
        for (int j = 0; j < 25; ++j) {
            const int s = y * 25 + j;
            atomicAdd(dst + ((size_t)(b * NS + s)) * ncols + c, acc[j]);
        }
    }
}

// K4: scale accumulated sums by rcp
__global__ __launch_bounds__(256) void k_fin(float* __restrict__ out,
                                             const float* __restrict__ rcp) {
    const int i = blockIdx.x * 256 + threadIdx.x;
    if (i < NB * NS * NCLS) {
        const int b = i / (NS * NCLS);
        const int s = (i / NCLS) % NS;
        out[i] *= rcp[b * NS + s];
    } else if (i < NB * NS * NCLS + NB * NS * NC) {
        const int j = i - NB * NS * NCLS;
        const int b = j / (NS * NC);
        const int s = (j >> 8) % NS;
        out[EMB_BASE + j] *= rcp[b * NS + s];
    }
}

// K5 (MFMA): proto_masks[b][s][px] = sum_c emb[b][s][c] * mf[b][c][px]
// C tile [112 s][128 px], K=256 fully unrolled in 8 steps of 32.
// A: full tile staged once in LDS [112][A_STRIDE] bf16 (59 KB).
// B: loaded per-lane straight from global into fragment registers
//    (each mf element consumed by exactly one lane -> no reuse, no LDS).
__global__ __launch_bounds__(256) void k_masks_mfma(const float* __restrict__ emb,
                                                    const float* __restrict__ mf,
                                                    float* __restrict__ outm) {
    __shared__ unsigned short As[112 * A_STRIDE];   // 59136 B

    const int b   = blockIdx.y;
    const int px0 = blockIdx.x * 128;
    const int tid = threadIdx.x;
    const float* mfb  = mf  + (size_t)b * NC * NPX;
    const float* embb = emb + (size_t)b * NS * NC;

    // ---- stage A: emb[b] f32 -> bf16, rows 100..111 zero ----
    for (int u = tid; u < NS * 64; u += 256) {          // 6400 quads
        const int s  = u >> 6;
        const int k4 = (u & 63) << 2;
        const float4 v = *(const float4*)(embb + (size_t)s * NC + k4);
        bf16x4 pv;
        pv[0] = (short)f2bf(v.x); pv[1] = (short)f2bf(v.y);
        pv[2] = (short)f2bf(v.z); pv[3] = (short)f2bf(v.w);
        *(bf16x4*)&As[s * A_STRIDE + k4] = pv;
    }
    {
        bf16x4 z; z[0] = 0; z[1] = 0; z[2] = 0; z[3] = 0;
        for (int u = tid; u < (12 * A_STRIDE) / 4; u += 256)   // 792 quads
            *(bf16x4*)&As[100 * A_STRIDE + u * 4] = z;
    }
    __syncthreads();

    const int lane = tid & 63;
    const int wv   = tid >> 6;        // wave -> px columns wv*32 .. wv*32+31
    const int lg   = lane >> 4;       // 0..3 -> k chunk lg*8
    const int ll   = lane & 15;
    const int pxA  = px0 + wv * 32 + ll;   // fragment ct=0; ct=1 at +16

    f32x4 acc[7][2];
    #pragma unroll
    for (int st = 0; st < 7; ++st) {
        acc[st][0] = (f32x4)(0.f);
        acc[st][1] = (f32x4)(0.f);
    }

    #pragma unroll
    for (int kk = 0; kk < 8; ++kk) {
        // B fragments: lane l needs mf[k = kk*32 + lg*8 + j][pxA (+16)]
        float v0[8], v1[8];
        #pragma unroll
        for (int j = 0; j < 8; ++j) {
            const size_t ro = (size_t)(kk * 32 + lg * 8 + j) * NPX;
            v0[j] = mfb[ro + pxA];
            v1[j] = mfb[ro + pxA + 16];
        }
        bf16x8 bf0, bf1;
        #pragma unroll
        for (int j = 0; j < 8; ++j) {
            bf0[j] = (short)f2bf(v0[j]);
            bf1[j] = (short)f2bf(v1[j]);
        }

        #pragma unroll
        for (int st = 0; st < 7; ++st) {
            const bf16x8 af = *(const bf16x8*)&As[(st * 16 + ll) * A_STRIDE + kk * 32 + lg * 8];
            acc[st][0] = __builtin_amdgcn_mfma_f32_16x16x32_bf16(af, bf0, acc[st][0], 0, 0, 0);
            acc[st][1] = __builtin_amdgcn_mfma_f32_16x16x32_bf16(af, bf1, acc[st][1], 0, 0, 0);
        }
    }

    // epilogue: D col = ll -> px, row = st*16 + lg*4 + r -> s
    #pragma unroll
    for (int st = 0; st < 7; ++st) {
        #pragma unroll
        for (int ct = 0; ct < 2; ++ct) {
            #pragma unroll
            for (int r = 0; r < 4; ++r) {
                const int s = st * 16 + lg * 4 + r;
                if (s < NS)
                    outm[((size_t)(b * NS + s)) * NPX + px0 + wv * 32 + ct * 16 + ll] = acc[st][ct][r];
            }
        }
    }
}

extern "C" void kernel_launch(void* const* d_in, const int* in_sizes, int n_in,
                              void* d_out, int out_size, void* d_ws, size_t ws_size,
                              hipStream_t stream) {
    const float* qcls = (const float*)d_in[0];
    const float* qemb = (const float*)d_in[1];
    const float* qsig = (const float*)d_in[2];
    const float* seed = (const float*)d_in[3];
    const float* mf   = (const float*)d_in[4];
    const int*   mask = (const int*)d_in[5];

    float* out       = (float*)d_out;
    float* out_cls   = out;
    float* out_masks = out + MASKS_BASE;
    float* out_emb   = out + EMB_BASE;

    float* w   = (float*)d_ws;                    // [4][100][2700]
    float* rcp = w + (size_t)NB * NS * LQ;        // [400]

    hipMemsetAsync(out_cls, 0, (size_t)NB * NS * NCLS * sizeof(float), stream);
    hipMemsetAsync(out_emb, 0, (size_t)NB * NS * NC * sizeof(float), stream);

    k_sim   <<<dim3(85, NB),     256, 0, stream>>>(qsig, seed, mask, w);
    k_denom <<<dim3(NS, NB),     256, 0, stream>>>(w, rcp);
    k_embcls<<<dim3(6, NB, 22),  256, 0, stream>>>(w, qemb, qcls, out_emb, out_cls);
    k_fin   <<<527,              256, 0, stream>>>(out, rcp);
    k_masks_mfma<<<dim3(200, NB), 256, 0, stream>>>(out_emb, mf, out_masks);
}